// Round 11
// baseline (103.599 us; speedup 1.0000x reference)
//
#include <hip/hip_runtime.h>
#include <hip/hip_fp16.h>

// RoIAlign (legacy, grid spacing roi/(P-1), PH=PW=8, zero for OOR samples)
// fused with 2x2 stride-1 max-pool -> out [R, C=256, 7, 7] float32.
//
// R11 = R9 (best measured, 80 us) + spatial roi sort + XCD-chunked
// assignment. Rois sorted by (batch, y, x) center; sorted chunk x is
// processed by blocks with blockIdx%8 == x (same XCD) so concurrent blocks
// share gather footprints in the 4MB per-XCD L2 (features are L3-resident;
// avg pixel record is re-fetched ~4.7x across rois).

#define FH 200
#define FW 272
#define FC 256
#define FHW (FH * FW)          // 54400
#define SPATIAL_SCALE 0.25f
#define RECB 512               // bytes per pixel record (256 ch * 2 B)
#define ROWB (FW * RECB)       // bytes per feature row
#define NBLK 512               // persistent grid (2 blocks/CU * 256 CU)

// ---------------- transpose+convert [B,C,HW] f32 -> [B,HW,C] f16 ----------
__global__ __launch_bounds__(256) void transpose_f16_kernel(
    const float* __restrict__ in, __half* __restrict__ outT)
{
    __shared__ float tile[64][65];
    const int hw0  = blockIdx.x * 64;
    const int c0   = blockIdx.y * 64;
    const int b    = blockIdx.z;
    const int lane = threadIdx.x & 63;
    const int sub  = threadIdx.x >> 6;   // 0..3

    const float* inb = in + (size_t)b * FC * FHW;
    #pragma unroll
    for (int i = 0; i < 16; ++i) {
        const int c = sub * 16 + i;
        tile[c][lane] = inb[(size_t)(c0 + c) * FHW + hw0 + lane];
    }
    __syncthreads();
    __half* outb = outT + (size_t)b * FHW * FC;
    #pragma unroll
    for (int i = 0; i < 16; ++i) {
        const int hw = sub * 16 + i;
        outb[(size_t)(hw0 + hw) * FC + c0 + lane] = __float2half(tile[lane][hw]);
    }
}

// ---------------- one-block bitonic sort of roi indices -------------------
// key = (batch << 18) | (y_center_feat << 9) | x_center_feat
__global__ __launch_bounds__(1024) void sort_rois_kernel(
    const float* __restrict__ rois, int R, int* __restrict__ order)
{
    __shared__ int s_key[2048];
    __shared__ int s_idx[2048];
    const int t = threadIdx.x;

    for (int i = t; i < 2048; i += 1024) {
        if (i < R) {
            const float b  = rois[i * 5 + 0];
            const float yc = (rois[i * 5 + 2] + rois[i * 5 + 4]) * 0.5f * SPATIAL_SCALE;
            const float xc = (rois[i * 5 + 1] + rois[i * 5 + 3]) * 0.5f * SPATIAL_SCALE;
            int yi = (int)fminf(fmaxf(yc, 0.0f), 511.0f);
            int xi = (int)fminf(fmaxf(xc, 0.0f), 511.0f);
            s_key[i] = (((int)b) << 18) | (yi << 9) | xi;
            s_idx[i] = i;
        } else {
            s_key[i] = 0x7FFFFFFF;
            s_idx[i] = i;
        }
    }
    __syncthreads();

    for (int k = 2; k <= 2048; k <<= 1) {
        for (int j = k >> 1; j > 0; j >>= 1) {
            #pragma unroll 2
            for (int i = t; i < 2048; i += 1024) {
                const int ixj = i ^ j;
                if (ixj > i) {
                    const bool up = ((i & k) == 0);
                    const int ka = s_key[i], kb = s_key[ixj];
                    if ((ka > kb) == up) {
                        s_key[i] = kb; s_key[ixj] = ka;
                        const int ia = s_idx[i];
                        s_idx[i] = s_idx[ixj]; s_idx[ixj] = ia;
                    }
                }
            }
            __syncthreads();
        }
    }
    for (int i = t; i < R; i += 1024) order[i] = s_idx[i];
}

// ---------------- main: DMA-staged gather + fused pool --------------------
__global__ __launch_bounds__(256, 2) void roi_align_max_dma_kernel(
    const __half* __restrict__ featT,   // [B, H, W, C] f16
    const float* __restrict__ rois,     // [R, 5]
    const int* __restrict__ order,      // sorted roi indices
    float* __restrict__ out,            // [R, C, 7, 7]
    int R)
{
    __shared__ int      s_boff[64];         // record byte offset per grid pt
    __shared__ float    s_w0[64], s_w1[64], s_w2[64], s_w3[64];
    __shared__ uint32_t s_buf[3][4096];     // 3 x 16 KB row staging
    __shared__ __half   s_out16[FC * 49];   // 24.5 KB pooled output

    const int tid  = threadIdx.x;
    const int lane = tid & 63;
    const int wid  = tid >> 6;     // wave 0..3
    const int cp   = tid & 127;    // channel pair: channels 2cp, 2cp+1
    const int h    = tid >> 7;     // pw-half: 0 -> pw 0..3, 1 -> pw 3..7
    const char* fbytes = (const char*)featT;

    // issue one aligned row's 16 x 1KB chunks (4 per wave) via DMA
    auto issue_row = [&](int row) {
        const int rm  = row * 8;
        const int bsel = row % 3;
        #pragma unroll
        for (int i = 0; i < 4; ++i) {
            const int q  = wid * 4 + i;     // chunk 0..15
            const int fr = q >> 3;          // feature row 0/1
            const int pw = q & 7;           // grid col
            const char* g = fbytes + s_boff[rm + pw] + fr * ROWB + lane * 16;
            __builtin_amdgcn_global_load_lds(
                (const uint32_t*)g, &s_buf[bsel][q * 256], 16, 0, 0);
        }
    };

    auto process = [&](int r) {
        // ---- per-roi setup (64 grid points) ----
        if (tid < 64) {
            const float b  = rois[r * 5 + 0];
            const float x1 = rois[r * 5 + 1] * SPATIAL_SCALE;
            const float y1 = rois[r * 5 + 2] * SPATIAL_SCALE;
            const float x2 = rois[r * 5 + 3] * SPATIAL_SCALE;
            const float y2 = rois[r * 5 + 4] * SPATIAL_SCALE;
            const float bin_h = fmaxf(y2 - y1, 0.0f) * (1.0f / 7.0f);
            const float bin_w = fmaxf(x2 - x1, 0.0f) * (1.0f / 7.0f);

            const int ph = tid >> 3;
            const int pw = tid & 7;
            const float hh = y1 + (float)ph * bin_h;
            const float ww = x1 + (float)pw * bin_w;

            const bool valid = (hh >= 0.0f) && (hh < (float)FH) &&
                               (ww >= 0.0f) && (ww < (float)FW);
            // legacy: clip floor() into [0, H-2]; fractions NOT re-clamped
            const float h0 = fminf(fmaxf(floorf(hh), 0.0f), (float)(FH - 2));
            const float w0 = fminf(fmaxf(floorf(ww), 0.0f), (float)(FW - 2));
            const float fh = hh - h0;
            const float fw = ww - w0;
            const float v  = valid ? 1.0f : 0.0f;

            s_boff[tid] = ((int)b * FHW + (int)h0 * FW + (int)w0) * RECB;
            s_w0[tid] = (1.0f - fh) * (1.0f - fw) * v;
            s_w1[tid] = (1.0f - fh) * fw * v;
            s_w2[tid] = fh * (1.0f - fw) * v;
            s_w3[tid] = fh * fw * v;
        }
        __syncthreads();

        issue_row(0);
        issue_row(1);

        const int npt = h ? 5 : 4;      // points this half computes
        const int ncm = h ? 4 : 3;      // col-max outputs
        const int pw0 = h ? 3 : 0;
        const int owb = h ? 3 : 0;
        float2 prev[4];

        #pragma unroll
        for (int ar = 0; ar < 8; ++ar) {
            if (ar == 7) { asm volatile("s_waitcnt vmcnt(0)" ::: "memory"); }
            else         { asm volatile("s_waitcnt vmcnt(4)" ::: "memory"); }
            __builtin_amdgcn_sched_barrier(0);
            __builtin_amdgcn_s_barrier();

            // compute aligned row ar from staged LDS
            const __half2* bh2 = (const __half2*)s_buf[ar % 3];
            float2 v[5];
            #pragma unroll
            for (int k = 0; k < 5; ++k) {
                if (k < npt) {
                    const int pw = pw0 + k;
                    const int m  = ar * 8 + pw;
                    const float2 a00 = __half22float2(bh2[pw * 256 + cp]);
                    const float2 a01 = __half22float2(bh2[pw * 256 + 128 + cp]);
                    const float2 a10 = __half22float2(bh2[(8 + pw) * 256 + cp]);
                    const float2 a11 = __half22float2(bh2[(8 + pw) * 256 + 128 + cp]);
                    const float w0v = s_w0[m], w1v = s_w1[m];
                    const float w2v = s_w2[m], w3v = s_w3[m];
                    v[k].x = a00.x * w0v + a01.x * w1v + a10.x * w2v + a11.x * w3v;
                    v[k].y = a00.y * w0v + a01.y * w1v + a10.y * w2v + a11.y * w3v;
                }
            }
            float2 cur[4];
            #pragma unroll
            for (int j = 0; j < 4; ++j) {
                if (j < ncm) {
                    cur[j].x = fmaxf(v[j].x, v[j + 1].x);
                    cur[j].y = fmaxf(v[j].y, v[j + 1].y);
                }
            }
            if (ar > 0) {
                const int ob = (ar - 1) * 7 + owb;
                #pragma unroll
                for (int j = 0; j < 4; ++j) {
                    if (j < ncm) {
                        s_out16[(2 * cp)     * 49 + ob + j] =
                            __float2half(fmaxf(prev[j].x, cur[j].x));
                        s_out16[(2 * cp + 1) * 49 + ob + j] =
                            __float2half(fmaxf(prev[j].y, cur[j].y));
                    }
                }
            }
            #pragma unroll
            for (int j = 0; j < 4; ++j) prev[j] = cur[j];

            if (ar < 6) issue_row(ar + 2);
        }
        __syncthreads();

        // dense float4 writeout (f16 -> f32) of this roi's [C,7,7] slab
        float4* o4 = (float4*)(out + (size_t)r * (FC * 49));
        #pragma unroll
        for (int k = 0; k < 13; ++k) {
            const int idx = k * 256 + tid;      // group of 4 halves
            if (idx < (FC * 49 / 4)) {
                const __half2* sh2 = (const __half2*)(s_out16 + idx * 4);
                const float2 lo = __half22float2(sh2[0]);
                const float2 hi = __half22float2(sh2[1]);
                o4[idx] = make_float4(lo.x, lo.y, hi.x, hi.y);
            }
        }
        __syncthreads();   // s_out16/s_buf safe to reuse for next roi
    };

    if (R >= NBLK) {
        // XCD-chunked: sorted chunk x goes to blocks on XCD x (= bid % 8)
        const int chunk = (R + 7) >> 3;
        const int xcd = blockIdx.x & 7;
        const int sub = blockIdx.x >> 3;        // 0..63
        for (int p = sub; p < chunk; p += (NBLK >> 3)) {
            const int pos = xcd * chunk + p;
            if (pos >= R) break;
            process(order[pos]);
        }
    } else {
        process(order[blockIdx.x]);
    }
}

// ---------------- fallback (NCHW direct) if ws too small ------------------
__global__ __launch_bounds__(256) void roi_align_max_kernel(
    const float* __restrict__ feat, const float* __restrict__ rois,
    float* __restrict__ out, int R)
{
    __shared__ int   s_off[64];
    __shared__ float s_w0[64], s_w1[64], s_w2[64], s_w3[64];
    __shared__ int   s_base;

    const int r   = blockIdx.x;
    const int tid = threadIdx.x;

    if (tid < 64) {
        const float b  = rois[r * 5 + 0];
        const float x1 = rois[r * 5 + 1] * SPATIAL_SCALE;
        const float y1 = rois[r * 5 + 2] * SPATIAL_SCALE;
        const float x2 = rois[r * 5 + 3] * SPATIAL_SCALE;
        const float y2 = rois[r * 5 + 4] * SPATIAL_SCALE;
        const float bin_h = fmaxf(y2 - y1, 0.0f) * (1.0f / 7.0f);
        const float bin_w = fmaxf(x2 - x1, 0.0f) * (1.0f / 7.0f);
        const int ph = tid >> 3;
        const int pw = tid & 7;
        const float h = y1 + (float)ph * bin_h;
        const float w = x1 + (float)pw * bin_w;
        const bool valid = (h >= 0.0f) && (h < (float)FH) &&
                           (w >= 0.0f) && (w < (float)FW);
        const float h0 = fminf(fmaxf(floorf(h), 0.0f), (float)(FH - 2));
        const float w0 = fminf(fmaxf(floorf(w), 0.0f), (float)(FW - 2));
        const float fh = h - h0;
        const float fw = w - w0;
        const float v  = valid ? 1.0f : 0.0f;
        s_off[tid] = (int)h0 * FW + (int)w0;
        s_w0[tid] = (1.0f - fh) * (1.0f - fw) * v;
        s_w1[tid] = (1.0f - fh) * fw * v;
        s_w2[tid] = fh * (1.0f - fw) * v;
        s_w3[tid] = fh * fw * v;
        if (tid == 0) s_base = (int)b * (FC * FHW);
    }
    __syncthreads();

    const int c = tid;
    const float* __restrict__ f = feat + s_base + c * FHW;
    float* __restrict__ outp = out + ((size_t)r * FC + c) * 49;

    float prev[8];
    for (int ph = 0; ph < 8; ++ph) {
        float cur[8];
        #pragma unroll
        for (int pw = 0; pw < 8; ++pw) {
            const int m = ph * 8 + pw;
            const int o = s_off[m];
            cur[pw] = f[o] * s_w0[m] + f[o + 1] * s_w1[m]
                    + f[o + FW] * s_w2[m] + f[o + FW + 1] * s_w3[m];
        }
        if (ph > 0) {
            #pragma unroll
            for (int ow = 0; ow < 7; ++ow)
                outp[(ph - 1) * 7 + ow] =
                    fmaxf(fmaxf(prev[ow], prev[ow + 1]),
                          fmaxf(cur[ow],  cur[ow + 1]));
        }
        #pragma unroll
        for (int pw = 0; pw < 8; ++pw) prev[pw] = cur[pw];
    }
}

extern "C" void kernel_launch(void* const* d_in, const int* in_sizes, int n_in,
                              void* d_out, int out_size, void* d_ws, size_t ws_size,
                              hipStream_t stream) {
    const float* feat = (const float*)d_in[0];
    const float* rois = (const float*)d_in[1];
    float* out = (float*)d_out;
    const int R = in_sizes[1] / 5;
    if (R <= 0) return;

    const size_t featT_bytes = (size_t)2 * FC * FHW * sizeof(__half);  // 55.7 MB
    const size_t needed = featT_bytes + 2048 * sizeof(int);
    if (ws_size >= needed && R <= 2048) {
        __half* featT = (__half*)d_ws;
        int* order = (int*)((char*)d_ws + featT_bytes);
        transpose_f16_kernel<<<dim3(FHW / 64, FC / 64, 2), 256, 0, stream>>>(feat, featT);
        sort_rois_kernel<<<1, 1024, 0, stream>>>(rois, R, order);
        const int nblk = (R < NBLK) ? R : NBLK;
        roi_align_max_dma_kernel<<<nblk, 256, 0, stream>>>(featT, rois, order, out, R);
    } else {
        roi_align_max_kernel<<<R, 256, 0, stream>>>(feat, rois, out, R);
    }
}

// Round 12
// 79.639 us; speedup vs baseline: 1.3008x; 1.3008x over previous
//
#include <hip/hip_runtime.h>
#include <hip/hip_fp16.h>

// RoIAlign (legacy, grid spacing roi/(P-1), PH=PW=8, zero for OOR samples)
// fused with 2x2 stride-1 max-pool -> out [R, C=256, 7, 7] float32.
//
// R12 = exact revert to R9 (best measured: 80.0 us).
// Structure: transpose+f16 channels-last (27 us, streaming floor) + DMA
// main kernel (global_load_lds staging, triple-buffered rows, counted
// vmcnt, 512 persistent blocks). R10 (issue-early + transpose-v2) and
// R11 (roi sort + XCD chunking) both regressed; R5/R8 showed register
// batching spills; R7 showed channel-split doubles write traffic.

#define FH 200
#define FW 272
#define FC 256
#define FHW (FH * FW)          // 54400
#define SPATIAL_SCALE 0.25f
#define RECB 512               // bytes per pixel record (256 ch * 2 B)
#define ROWB (FW * RECB)       // bytes per feature row
#define NBLK 512               // persistent grid (2 blocks/CU * 256 CU)

// ---------------- transpose+convert [B,C,HW] f32 -> [B,HW,C] f16 ----------
__global__ __launch_bounds__(256) void transpose_f16_kernel(
    const float* __restrict__ in, __half* __restrict__ outT)
{
    __shared__ float tile[64][65];
    const int hw0  = blockIdx.x * 64;
    const int c0   = blockIdx.y * 64;
    const int b    = blockIdx.z;
    const int lane = threadIdx.x & 63;
    const int sub  = threadIdx.x >> 6;   // 0..3

    const float* inb = in + (size_t)b * FC * FHW;
    #pragma unroll
    for (int i = 0; i < 16; ++i) {
        const int c = sub * 16 + i;
        tile[c][lane] = inb[(size_t)(c0 + c) * FHW + hw0 + lane];
    }
    __syncthreads();
    __half* outb = outT + (size_t)b * FHW * FC;
    #pragma unroll
    for (int i = 0; i < 16; ++i) {
        const int hw = sub * 16 + i;
        outb[(size_t)(hw0 + hw) * FC + c0 + lane] = __float2half(tile[lane][hw]);
    }
}

// ---------------- main: DMA-staged gather + fused pool --------------------
__global__ __launch_bounds__(256, 2) void roi_align_max_dma_kernel(
    const __half* __restrict__ featT,   // [B, H, W, C] f16
    const float* __restrict__ rois,     // [R, 5]
    float* __restrict__ out,            // [R, C, 7, 7]
    int R)
{
    __shared__ int      s_boff[64];         // record byte offset per grid pt
    __shared__ float    s_w0[64], s_w1[64], s_w2[64], s_w3[64];
    __shared__ uint32_t s_buf[3][4096];     // 3 x 16 KB row staging
    __shared__ __half   s_out16[FC * 49];   // 24.5 KB pooled output

    const int tid  = threadIdx.x;
    const int lane = tid & 63;
    const int wid  = tid >> 6;     // wave 0..3
    const int cp   = tid & 127;    // channel pair: channels 2cp, 2cp+1
    const int h    = tid >> 7;     // pw-half: 0 -> pw 0..3, 1 -> pw 3..7
    const char* fbytes = (const char*)featT;

    // issue one aligned row's 16 x 1KB chunks (4 per wave) via DMA
    auto issue_row = [&](int row) {
        const int rm  = row * 8;
        const int bsel = row % 3;
        #pragma unroll
        for (int i = 0; i < 4; ++i) {
            const int q  = wid * 4 + i;     // chunk 0..15
            const int fr = q >> 3;          // feature row 0/1
            const int pw = q & 7;           // grid col
            const char* g = fbytes + s_boff[rm + pw] + fr * ROWB + lane * 16;
            __builtin_amdgcn_global_load_lds(
                (const uint32_t*)g, &s_buf[bsel][q * 256], 16, 0, 0);
        }
    };

    for (int r = blockIdx.x; r < R; r += NBLK) {
        // ---- per-roi setup (64 grid points) ----
        if (tid < 64) {
            const float b  = rois[r * 5 + 0];
            const float x1 = rois[r * 5 + 1] * SPATIAL_SCALE;
            const float y1 = rois[r * 5 + 2] * SPATIAL_SCALE;
            const float x2 = rois[r * 5 + 3] * SPATIAL_SCALE;
            const float y2 = rois[r * 5 + 4] * SPATIAL_SCALE;
            const float bin_h = fmaxf(y2 - y1, 0.0f) * (1.0f / 7.0f);
            const float bin_w = fmaxf(x2 - x1, 0.0f) * (1.0f / 7.0f);

            const int ph = tid >> 3;
            const int pw = tid & 7;
            const float hh = y1 + (float)ph * bin_h;
            const float ww = x1 + (float)pw * bin_w;

            const bool valid = (hh >= 0.0f) && (hh < (float)FH) &&
                               (ww >= 0.0f) && (ww < (float)FW);
            // legacy: clip floor() into [0, H-2]; fractions NOT re-clamped
            const float h0 = fminf(fmaxf(floorf(hh), 0.0f), (float)(FH - 2));
            const float w0 = fminf(fmaxf(floorf(ww), 0.0f), (float)(FW - 2));
            const float fh = hh - h0;
            const float fw = ww - w0;
            const float v  = valid ? 1.0f : 0.0f;

            s_boff[tid] = ((int)b * FHW + (int)h0 * FW + (int)w0) * RECB;
            s_w0[tid] = (1.0f - fh) * (1.0f - fw) * v;
            s_w1[tid] = (1.0f - fh) * fw * v;
            s_w2[tid] = fh * (1.0f - fw) * v;
            s_w3[tid] = fh * fw * v;
        }
        __syncthreads();

        issue_row(0);
        issue_row(1);

        const int npt = h ? 5 : 4;      // points this half computes
        const int ncm = h ? 4 : 3;      // col-max outputs
        const int pw0 = h ? 3 : 0;
        const int owb = h ? 3 : 0;
        float2 prev[4];

        #pragma unroll
        for (int ar = 0; ar < 8; ++ar) {
            if (ar == 7) { asm volatile("s_waitcnt vmcnt(0)" ::: "memory"); }
            else         { asm volatile("s_waitcnt vmcnt(4)" ::: "memory"); }
            __builtin_amdgcn_sched_barrier(0);
            __builtin_amdgcn_s_barrier();

            // compute aligned row ar from staged LDS
            const __half2* bh2 = (const __half2*)s_buf[ar % 3];
            float2 v[5];
            #pragma unroll
            for (int k = 0; k < 5; ++k) {
                if (k < npt) {
                    const int pw = pw0 + k;
                    const int m  = ar * 8 + pw;
                    const float2 a00 = __half22float2(bh2[pw * 256 + cp]);
                    const float2 a01 = __half22float2(bh2[pw * 256 + 128 + cp]);
                    const float2 a10 = __half22float2(bh2[(8 + pw) * 256 + cp]);
                    const float2 a11 = __half22float2(bh2[(8 + pw) * 256 + 128 + cp]);
                    const float w0v = s_w0[m], w1v = s_w1[m];
                    const float w2v = s_w2[m], w3v = s_w3[m];
                    v[k].x = a00.x * w0v + a01.x * w1v + a10.x * w2v + a11.x * w3v;
                    v[k].y = a00.y * w0v + a01.y * w1v + a10.y * w2v + a11.y * w3v;
                }
            }
            float2 cur[4];
            #pragma unroll
            for (int j = 0; j < 4; ++j) {
                if (j < ncm) {
                    cur[j].x = fmaxf(v[j].x, v[j + 1].x);
                    cur[j].y = fmaxf(v[j].y, v[j + 1].y);
                }
            }
            if (ar > 0) {
                const int ob = (ar - 1) * 7 + owb;
                #pragma unroll
                for (int j = 0; j < 4; ++j) {
                    if (j < ncm) {
                        s_out16[(2 * cp)     * 49 + ob + j] =
                            __float2half(fmaxf(prev[j].x, cur[j].x));
                        s_out16[(2 * cp + 1) * 49 + ob + j] =
                            __float2half(fmaxf(prev[j].y, cur[j].y));
                    }
                }
            }
            #pragma unroll
            for (int j = 0; j < 4; ++j) prev[j] = cur[j];

            if (ar < 6) issue_row(ar + 2);
        }
        __syncthreads();

        // dense float4 writeout (f16 -> f32) of this roi's [C,7,7] slab
        float4* o4 = (float4*)(out + (size_t)r * (FC * 49));
        #pragma unroll
        for (int k = 0; k < 13; ++k) {
            const int idx = k * 256 + tid;      // group of 4 halves
            if (idx < (FC * 49 / 4)) {
                const __half2* sh2 = (const __half2*)(s_out16 + idx * 4);
                const float2 lo = __half22float2(sh2[0]);
                const float2 hi = __half22float2(sh2[1]);
                o4[idx] = make_float4(lo.x, lo.y, hi.x, hi.y);
            }
        }
        __syncthreads();   // s_out16/s_buf safe to reuse for next roi
    }
}

// ---------------- fallback (NCHW direct) if ws too small ------------------
__global__ __launch_bounds__(256) void roi_align_max_kernel(
    const float* __restrict__ feat, const float* __restrict__ rois,
    float* __restrict__ out, int R)
{
    __shared__ int   s_off[64];
    __shared__ float s_w0[64], s_w1[64], s_w2[64], s_w3[64];
    __shared__ int   s_base;

    const int r   = blockIdx.x;
    const int tid = threadIdx.x;

    if (tid < 64) {
        const float b  = rois[r * 5 + 0];
        const float x1 = rois[r * 5 + 1] * SPATIAL_SCALE;
        const float y1 = rois[r * 5 + 2] * SPATIAL_SCALE;
        const float x2 = rois[r * 5 + 3] * SPATIAL_SCALE;
        const float y2 = rois[r * 5 + 4] * SPATIAL_SCALE;
        const float bin_h = fmaxf(y2 - y1, 0.0f) * (1.0f / 7.0f);
        const float bin_w = fmaxf(x2 - x1, 0.0f) * (1.0f / 7.0f);
        const int ph = tid >> 3;
        const int pw = tid & 7;
        const float h = y1 + (float)ph * bin_h;
        const float w = x1 + (float)pw * bin_w;
        const bool valid = (h >= 0.0f) && (h < (float)FH) &&
                           (w >= 0.0f) && (w < (float)FW);
        const float h0 = fminf(fmaxf(floorf(h), 0.0f), (float)(FH - 2));
        const float w0 = fminf(fmaxf(floorf(w), 0.0f), (float)(FW - 2));
        const float fh = h - h0;
        const float fw = w - w0;
        const float v  = valid ? 1.0f : 0.0f;
        s_off[tid] = (int)h0 * FW + (int)w0;
        s_w0[tid] = (1.0f - fh) * (1.0f - fw) * v;
        s_w1[tid] = (1.0f - fh) * fw * v;
        s_w2[tid] = fh * (1.0f - fw) * v;
        s_w3[tid] = fh * fw * v;
        if (tid == 0) s_base = (int)b * (FC * FHW);
    }
    __syncthreads();

    const int c = tid;
    const float* __restrict__ f = feat + s_base + c * FHW;
    float* __restrict__ outp = out + ((size_t)r * FC + c) * 49;

    float prev[8];
    for (int ph = 0; ph < 8; ++ph) {
        float cur[8];
        #pragma unroll
        for (int pw = 0; pw < 8; ++pw) {
            const int m = ph * 8 + pw;
            const int o = s_off[m];
            cur[pw] = f[o] * s_w0[m] + f[o + 1] * s_w1[m]
                    + f[o + FW] * s_w2[m] + f[o + FW + 1] * s_w3[m];
        }
        if (ph > 0) {
            #pragma unroll
            for (int ow = 0; ow < 7; ++ow)
                outp[(ph - 1) * 7 + ow] =
                    fmaxf(fmaxf(prev[ow], prev[ow + 1]),
                          fmaxf(cur[ow],  cur[ow + 1]));
        }
        #pragma unroll
        for (int pw = 0; pw < 8; ++pw) prev[pw] = cur[pw];
    }
}

extern "C" void kernel_launch(void* const* d_in, const int* in_sizes, int n_in,
                              void* d_out, int out_size, void* d_ws, size_t ws_size,
                              hipStream_t stream) {
    const float* feat = (const float*)d_in[0];
    const float* rois = (const float*)d_in[1];
    float* out = (float*)d_out;
    const int R = in_sizes[1] / 5;
    if (R <= 0) return;

    const size_t needed = (size_t)2 * FC * FHW * sizeof(__half);  // 55.7 MB
    if (ws_size >= needed) {
        __half* featT = (__half*)d_ws;
        transpose_f16_kernel<<<dim3(FHW / 64, FC / 64, 2), 256, 0, stream>>>(feat, featT);
        const int nblk = (R < NBLK) ? R : NBLK;
        roi_align_max_dma_kernel<<<nblk, 256, 0, stream>>>(featT, rois, out, R);
    } else {
        roi_align_max_kernel<<<R, 256, 0, stream>>>(feat, rois, out, R);
    }
}

// Round 13
// 79.435 us; speedup vs baseline: 1.3042x; 1.0026x over previous
//
#include <hip/hip_runtime.h>
#include <hip/hip_fp16.h>

// RoIAlign (legacy, grid spacing roi/(P-1), PH=PW=8, zero for OOR samples)
// fused with 2x2 stride-1 max-pool -> out [R, C=256, 7, 7] float32.
//
// R13 = R9 + CONTINUOUS cross-roi DMA pipeline (T3/T4 counted-vmcnt lesson):
//  - per-roi setup tables double-buffered; next roi's setup computed during
//    round 0, its rows 0,1 issued during rounds 6,7 (3-buffer rotation
//    continues across rois: base advances +8 mod 3).
//  - NO vmcnt(0) drain per roi (only at the block's final roi). All barriers
//    in the stream are raw s_barrier + lgkmcnt(0) (a __syncthreads would
//    re-introduce the vmcnt(0) drain).
//  - writeout is wave-uniform (13 stores/thread via clamp) so counted waits
//    stay exact: rounds 0,1 after a writeout use vmcnt(17) (13 stores + 4
//    younger row-loads), other rounds vmcnt(4).

#define FH 200
#define FW 272
#define FC 256
#define FHW (FH * FW)          // 54400
#define SPATIAL_SCALE 0.25f
#define RECB 512               // bytes per pixel record (256 ch * 2 B)
#define ROWB (FW * RECB)       // bytes per feature row
#define NBLK 512               // persistent grid (2 blocks/CU * 256 CU)

#define WAITV(N) asm volatile("s_waitcnt vmcnt(" #N ") lgkmcnt(0)" ::: "memory")

// ---------------- transpose+convert [B,C,HW] f32 -> [B,HW,C] f16 ----------
__global__ __launch_bounds__(256) void transpose_f16_kernel(
    const float* __restrict__ in, __half* __restrict__ outT)
{
    __shared__ float tile[64][65];
    const int hw0  = blockIdx.x * 64;
    const int c0   = blockIdx.y * 64;
    const int b    = blockIdx.z;
    const int lane = threadIdx.x & 63;
    const int sub  = threadIdx.x >> 6;   // 0..3

    const float* inb = in + (size_t)b * FC * FHW;
    #pragma unroll
    for (int i = 0; i < 16; ++i) {
        const int c = sub * 16 + i;
        tile[c][lane] = inb[(size_t)(c0 + c) * FHW + hw0 + lane];
    }
    __syncthreads();
    __half* outb = outT + (size_t)b * FHW * FC;
    #pragma unroll
    for (int i = 0; i < 16; ++i) {
        const int hw = sub * 16 + i;
        outb[(size_t)(hw0 + hw) * FC + c0 + lane] = __float2half(tile[lane][hw]);
    }
}

// ---------------- main: continuous DMA pipeline + fused pool --------------
__global__ __launch_bounds__(256, 2) void roi_align_max_dma_kernel(
    const __half* __restrict__ featT,   // [B, H, W, C] f16
    const float* __restrict__ rois,     // [R, 5]
    float* __restrict__ out,            // [R, C, 7, 7]
    int R)
{
    __shared__ int      s_boff[2][64];      // record byte offset per grid pt
    __shared__ float    s_w0[2][64], s_w1[2][64], s_w2[2][64], s_w3[2][64];
    __shared__ uint32_t s_buf[3][4096];     // 3 x 16 KB row staging
    __shared__ __half   s_out16[FC * 49];   // 24.5 KB pooled output

    const int tid  = threadIdx.x;
    const int lane = tid & 63;
    const int wid  = tid >> 6;     // wave 0..3
    const int cp   = tid & 127;    // channel pair: channels 2cp, 2cp+1
    const int h    = tid >> 7;     // pw-half: 0 -> pw 0..3, 1 -> pw 3..7
    const char* fbytes = (const char*)featT;

    // per-roi setup: 64 grid points into table set sb (wave 0 only)
    auto setup = [&](int r, int sb) {
        if (tid < 64) {
            const float b  = rois[r * 5 + 0];
            const float x1 = rois[r * 5 + 1] * SPATIAL_SCALE;
            const float y1 = rois[r * 5 + 2] * SPATIAL_SCALE;
            const float x2 = rois[r * 5 + 3] * SPATIAL_SCALE;
            const float y2 = rois[r * 5 + 4] * SPATIAL_SCALE;
            const float bin_h = fmaxf(y2 - y1, 0.0f) * (1.0f / 7.0f);
            const float bin_w = fmaxf(x2 - x1, 0.0f) * (1.0f / 7.0f);

            const int ph = tid >> 3;
            const int pw = tid & 7;
            const float hh = y1 + (float)ph * bin_h;
            const float ww = x1 + (float)pw * bin_w;

            const bool valid = (hh >= 0.0f) && (hh < (float)FH) &&
                               (ww >= 0.0f) && (ww < (float)FW);
            // legacy: clip floor() into [0, H-2]; fractions NOT re-clamped
            const float h0 = fminf(fmaxf(floorf(hh), 0.0f), (float)(FH - 2));
            const float w0 = fminf(fmaxf(floorf(ww), 0.0f), (float)(FW - 2));
            const float fh = hh - h0;
            const float fw = ww - w0;
            const float v  = valid ? 1.0f : 0.0f;

            s_boff[sb][tid] = ((int)b * FHW + (int)h0 * FW + (int)w0) * RECB;
            s_w0[sb][tid] = (1.0f - fh) * (1.0f - fw) * v;
            s_w1[sb][tid] = (1.0f - fh) * fw * v;
            s_w2[sb][tid] = fh * (1.0f - fw) * v;
            s_w3[sb][tid] = fh * fw * v;
        }
    };

    // issue one aligned row's 16 x 1KB chunks (4 per wave) via DMA
    auto issue_row = [&](int sb, int row, int bsel) {
        const int rm = row * 8;
        #pragma unroll
        for (int i = 0; i < 4; ++i) {
            const int q  = wid * 4 + i;     // chunk 0..15
            const int fr = q >> 3;          // feature row 0/1
            const int pw = q & 7;           // grid col
            const char* g = fbytes + s_boff[sb][rm + pw] + fr * ROWB + lane * 16;
            __builtin_amdgcn_global_load_lds(
                (const uint32_t*)g, &s_buf[bsel][q * 256], 16, 0, 0);
        }
    };

    int r = blockIdx.x;
    if (r >= R) return;
    int sb = 0, base = 0;
    bool first = true;

    setup(r, 0);
    asm volatile("s_waitcnt lgkmcnt(0)" ::: "memory");
    __builtin_amdgcn_sched_barrier(0);
    __builtin_amdgcn_s_barrier();
    issue_row(0, 0, 0);
    issue_row(0, 1, 1);

    const int npt = h ? 5 : 4;      // points this half computes
    const int ncm = h ? 4 : 3;      // col-max outputs
    const int pw0 = h ? 3 : 0;
    const int owb = h ? 3 : 0;

    while (true) {
        const int rn = r + NBLK;
        const bool has_next = (rn < R);
        float2 prev[4];

        #pragma unroll
        for (int ar = 0; ar < 8; ++ar) {
            // counted waits (vmcnt ledger; stores count too — writeout is
            // 13 uniform stores/thread, older than rows >= 2)
            if (ar <= 1) { if (first) WAITV(4); else WAITV(17); }
            else if (ar == 7) { if (has_next) WAITV(4); else WAITV(0); }
            else WAITV(4);
            __builtin_amdgcn_sched_barrier(0);
            __builtin_amdgcn_s_barrier();

            // compute aligned row ar from staged LDS
            const __half2* bh2 = (const __half2*)s_buf[(base + ar) % 3];
            float2 v[5];
            #pragma unroll
            for (int k = 0; k < 5; ++k) {
                if (k < npt) {
                    const int pw = pw0 + k;
                    const int m  = ar * 8 + pw;
                    const float2 a00 = __half22float2(bh2[pw * 256 + cp]);
                    const float2 a01 = __half22float2(bh2[pw * 256 + 128 + cp]);
                    const float2 a10 = __half22float2(bh2[(8 + pw) * 256 + cp]);
                    const float2 a11 = __half22float2(bh2[(8 + pw) * 256 + 128 + cp]);
                    const float w0v = s_w0[sb][m], w1v = s_w1[sb][m];
                    const float w2v = s_w2[sb][m], w3v = s_w3[sb][m];
                    v[k].x = a00.x * w0v + a01.x * w1v + a10.x * w2v + a11.x * w3v;
                    v[k].y = a00.y * w0v + a01.y * w1v + a10.y * w2v + a11.y * w3v;
                }
            }
            float2 cur[4];
            #pragma unroll
            for (int j = 0; j < 4; ++j) {
                if (j < ncm) {
                    cur[j].x = fmaxf(v[j].x, v[j + 1].x);
                    cur[j].y = fmaxf(v[j].y, v[j + 1].y);
                }
            }
            if (ar > 0) {
                const int ob = (ar - 1) * 7 + owb;
                #pragma unroll
                for (int j = 0; j < 4; ++j) {
                    if (j < ncm) {
                        s_out16[(2 * cp)     * 49 + ob + j] =
                            __float2half(fmaxf(prev[j].x, cur[j].x));
                        s_out16[(2 * cp + 1) * 49 + ob + j] =
                            __float2half(fmaxf(prev[j].y, cur[j].y));
                    }
                }
            }
            #pragma unroll
            for (int j = 0; j < 4; ++j) prev[j] = cur[j];

            // next-roi setup during round 0 (read by issues at rounds 6,7)
            if (ar == 0 && has_next) setup(rn, sb ^ 1);

            // keep the DMA rotation full
            if (ar < 6)        issue_row(sb, ar + 2, (base + ar + 2) % 3);
            else if (has_next) issue_row(sb ^ 1, ar - 6, (base + 8 + (ar - 6)) % 3);
        }

        // flush s_out16 ds_writes + barrier WITHOUT draining vmcnt
        asm volatile("s_waitcnt lgkmcnt(0)" ::: "memory");
        __builtin_amdgcn_sched_barrier(0);
        __builtin_amdgcn_s_barrier();

        // dense writeout (f16 -> f32), 13 uniform stores/thread (idx clamp)
        float4* o4 = (float4*)(out + (size_t)r * (FC * 49));
        #pragma unroll
        for (int k = 0; k < 13; ++k) {
            int idx = k * 256 + tid;
            idx = (idx > (FC * 49 / 4 - 1)) ? (FC * 49 / 4 - 1) : idx;
            const __half2* sh2 = (const __half2*)(s_out16 + idx * 4);
            const float2 lo = __half22float2(sh2[0]);
            const float2 hi = __half22float2(sh2[1]);
            o4[idx] = make_float4(lo.x, lo.y, hi.x, hi.y);
        }
        // next round-0 barrier separates these reads from future s_out16
        // writes (which first occur at next roi's ar=1, one more barrier on)

        if (!has_next) break;
        r = rn; sb ^= 1; base = (base + 2) % 3; first = false;
    }
}

// ---------------- fallback (NCHW direct) if ws too small ------------------
__global__ __launch_bounds__(256) void roi_align_max_kernel(
    const float* __restrict__ feat, const float* __restrict__ rois,
    float* __restrict__ out, int R)
{
    __shared__ int   s_off[64];
    __shared__ float s_w0[64], s_w1[64], s_w2[64], s_w3[64];
    __shared__ int   s_base;

    const int r   = blockIdx.x;
    const int tid = threadIdx.x;

    if (tid < 64) {
        const float b  = rois[r * 5 + 0];
        const float x1 = rois[r * 5 + 1] * SPATIAL_SCALE;
        const float y1 = rois[r * 5 + 2] * SPATIAL_SCALE;
        const float x2 = rois[r * 5 + 3] * SPATIAL_SCALE;
        const float y2 = rois[r * 5 + 4] * SPATIAL_SCALE;
        const float bin_h = fmaxf(y2 - y1, 0.0f) * (1.0f / 7.0f);
        const float bin_w = fmaxf(x2 - x1, 0.0f) * (1.0f / 7.0f);
        const int ph = tid >> 3;
        const int pw = tid & 7;
        const float h = y1 + (float)ph * bin_h;
        const float w = x1 + (float)pw * bin_w;
        const bool valid = (h >= 0.0f) && (h < (float)FH) &&
                           (w >= 0.0f) && (w < (float)FW);
        const float h0 = fminf(fmaxf(floorf(h), 0.0f), (float)(FH - 2));
        const float w0 = fminf(fmaxf(floorf(w), 0.0f), (float)(FW - 2));
        const float fh = h - h0;
        const float fw = w - w0;
        const float v  = valid ? 1.0f : 0.0f;
        s_off[tid] = (int)h0 * FW + (int)w0;
        s_w0[tid] = (1.0f - fh) * (1.0f - fw) * v;
        s_w1[tid] = (1.0f - fh) * fw * v;
        s_w2[tid] = fh * (1.0f - fw) * v;
        s_w3[tid] = fh * fw * v;
        if (tid == 0) s_base = (int)b * (FC * FHW);
    }
    __syncthreads();

    const int c = tid;
    const float* __restrict__ f = feat + s_base + c * FHW;
    float* __restrict__ outp = out + ((size_t)r * FC + c) * 49;

    float prev[8];
    for (int ph = 0; ph < 8; ++ph) {
        float cur[8];
        #pragma unroll
        for (int pw = 0; pw < 8; ++pw) {
            const int m = ph * 8 + pw;
            const int o = s_off[m];
            cur[pw] = f[o] * s_w0[m] + f[o + 1] * s_w1[m]
                    + f[o + FW] * s_w2[m] + f[o + FW + 1] * s_w3[m];
        }
        if (ph > 0) {
            #pragma unroll
            for (int ow = 0; ow < 7; ++ow)
                outp[(ph - 1) * 7 + ow] =
                    fmaxf(fmaxf(prev[ow], prev[ow + 1]),
                          fmaxf(cur[ow],  cur[ow + 1]));
        }
        #pragma unroll
        for (int pw = 0; pw < 8; ++pw) prev[pw] = cur[pw];
    }
}

extern "C" void kernel_launch(void* const* d_in, const int* in_sizes, int n_in,
                              void* d_out, int out_size, void* d_ws, size_t ws_size,
                              hipStream_t stream) {
    const float* feat = (const float*)d_in[0];
    const float* rois = (const float*)d_in[1];
    float* out = (float*)d_out;
    const int R = in_sizes[1] / 5;
    if (R <= 0) return;

    const size_t needed = (size_t)2 * FC * FHW * sizeof(__half);  // 55.7 MB
    if (ws_size >= needed) {
        __half* featT = (__half*)d_ws;
        transpose_f16_kernel<<<dim3(FHW / 64, FC / 64, 2), 256, 0, stream>>>(feat, featT);
        const int nblk = (R < NBLK) ? R : NBLK;
        roi_align_max_dma_kernel<<<nblk, 256, 0, stream>>>(featT, rois, out, R);
    } else {
        roi_align_max_kernel<<<R, 256, 0, stream>>>(feat, rois, out, R);
    }
}